// Round 1
// baseline (960.726 us; speedup 1.0000x reference)
//
#include <hip/hip_runtime.h>
#include <hip/hip_bf16.h>
#include <stdint.h>

// Problem constants
constexpr int cB = 4, cN = 512, cE = 512, cH = 32, cP = 128;
// D = 16, SCALING = 0.25 folded into Q at projection epilogue.

typedef __attribute__((ext_vector_type(8))) short bf16x8;
typedef __attribute__((ext_vector_type(4))) float f32x4;

__device__ __forceinline__ unsigned short f2bf(float f) {
    union { float f; unsigned u; } v; v.f = f;
    unsigned u = v.u;
    u += 0x7fffu + ((u >> 16) & 1u);   // RNE
    return (unsigned short)(u >> 16);
}
__device__ __forceinline__ float bf2f(unsigned short s) {
    union { unsigned u; float f; } v; v.u = ((unsigned)s) << 16;
    return v.f;
}

// ---------------- Kernel 1: LayerNorm(query) -> xn (f32) ----------------
__global__ __launch_bounds__(256) void ln_query_kernel(
    const float* __restrict__ q, const float* __restrict__ g,
    const float* __restrict__ b, float* __restrict__ xn)
{
    int row = blockIdx.x;          // 0..B*N-1
    int t = threadIdx.x;           // 256
    const float* xr = q + (size_t)row * cE;
    float2 v = *(const float2*)(xr + t * 2);
    float s = v.x + v.y;
    float ss = v.x * v.x + v.y * v.y;
    #pragma unroll
    for (int o = 32; o > 0; o >>= 1) {
        s  += __shfl_down(s, o, 64);
        ss += __shfl_down(ss, o, 64);
    }
    __shared__ float red[8];
    int wv = t >> 6, ln = t & 63;
    if (ln == 0) { red[wv] = s; red[wv + 4] = ss; }
    __syncthreads();
    if (t == 0) {
        float S = red[0] + red[1] + red[2] + red[3];
        float SS = red[4] + red[5] + red[6] + red[7];
        float mu = S * (1.0f / cE);
        float var = SS * (1.0f / cE) - mu * mu;
        red[0] = mu; red[1] = rsqrtf(var + 1e-5f);
    }
    __syncthreads();
    float mu = red[0], rs = red[1];
    float2 gg = *(const float2*)(g + t * 2);
    float2 bb2 = *(const float2*)(b + t * 2);
    float2 o2;
    o2.x = (v.x - mu) * rs * gg.x + bb2.x;
    o2.y = (v.y - mu) * rs * gg.y + bb2.y;
    *(float2*)(xn + (size_t)row * cE + t * 2) = o2;
}

// ---------------- Kernel 2: setup Wb' (bf16), S_h, cb_h ----------------
__global__ void setup_kernel(
    const float* __restrict__ Wb, const float* __restrict__ pg,
    const float* __restrict__ pb, const float* __restrict__ bbv,
    unsigned short* __restrict__ Wbp, float* __restrict__ Sh,
    float* __restrict__ cbh)
{
    int h = threadIdx.x;
    if (h < cH) {
        float s = 0.f, c = bbv[h];
        for (int p = 0; p < cP; ++p) {
            float wv = Wb[h * cP + p];
            float wp = wv * pg[p];
            s += wp;
            c += pb[p] * wv;
            Wbp[h * cP + p] = f2bf(wp);
        }
        Sh[h] = s; cbh[h] = c;
    }
}

// ------------- Kernel 3: Q/K projections (fp32 GEMM) + w from V tile -------------
// C = xn(2048x512) @ [Wq;Wk;Wv]^T  -> Q*0.25, K stored; V tile folded into w via Wf + atomics.
__global__ __launch_bounds__(64) void qkv_kernel(
    const float* __restrict__ xn,
    const float* __restrict__ Wq, const float* __restrict__ Wk,
    const float* __restrict__ Wv, const float* __restrict__ Wf,
    float* __restrict__ Q, float* __restrict__ K, float* __restrict__ w)
{
    int mtile = blockIdx.x & 31;      // 32 tiles of 64 rows
    int ntile = blockIdx.x >> 5;      // 24 tiles of 64 cols
    int mat = ntile >> 3;             // 0=Q 1=K 2=V
    int ncol0 = (ntile & 7) * 64;
    const float* W = (mat == 0) ? Wq : ((mat == 1) ? Wk : Wv);
    int rm = mtile * 64;
    int t = threadIdx.x;
    int tm = t >> 3, tn = t & 7;      // 8x8 thread grid, 8x8 micro-tile

    __shared__ float As[32][68];      // [k][m]
    __shared__ float Bs[32][68];      // [k][n]
    float acc[8][8];
    #pragma unroll
    for (int i = 0; i < 8; ++i)
        #pragma unroll
        for (int j = 0; j < 8; ++j) acc[i][j] = 0.f;

    for (int k0 = 0; k0 < cE; k0 += 32) {
        #pragma unroll
        for (int s = 0; s < 8; ++s) {
            int f = t + 64 * s;       // 0..511 float4 slots
            int row = f >> 3, kq = f & 7;
            float4 v = *(const float4*)(xn + (size_t)(rm + row) * cE + k0 + kq * 4);
            As[kq * 4 + 0][row] = v.x; As[kq * 4 + 1][row] = v.y;
            As[kq * 4 + 2][row] = v.z; As[kq * 4 + 3][row] = v.w;
            float4 u = *(const float4*)(W + (size_t)(ncol0 + row) * cE + k0 + kq * 4);
            Bs[kq * 4 + 0][row] = u.x; Bs[kq * 4 + 1][row] = u.y;
            Bs[kq * 4 + 2][row] = u.z; Bs[kq * 4 + 3][row] = u.w;
        }
        __syncthreads();
        #pragma unroll
        for (int kk = 0; kk < 32; ++kk) {
            float a[8], bv[8];
            #pragma unroll
            for (int i = 0; i < 8; ++i) a[i] = As[kk][tm * 8 + i];
            #pragma unroll
            for (int j = 0; j < 8; ++j) bv[j] = Bs[kk][tn * 8 + j];
            #pragma unroll
            for (int i = 0; i < 8; ++i)
                #pragma unroll
                for (int j = 0; j < 8; ++j) acc[i][j] = fmaf(a[i], bv[j], acc[i][j]);
        }
        __syncthreads();
    }

    if (mat < 2) {
        float scale = (mat == 0) ? 0.25f : 1.0f;
        float* dst = (mat == 0) ? Q : K;
        #pragma unroll
        for (int i = 0; i < 8; ++i) {
            int r = rm + tm * 8 + i;
            #pragma unroll
            for (int j = 0; j < 8; ++j)
                dst[(size_t)r * cE + ncol0 + tn * 8 + j] = acc[i][j] * scale;
        }
    } else {
        // V tile: fold into w[b*N+j][h] = sum_d V*Wf  (8 cols all in one head)
        int col0 = ncol0 + tn * 8;
        int h = col0 >> 4;
        float wf[8];
        #pragma unroll
        for (int j = 0; j < 8; ++j) wf[j] = Wf[col0 + j];
        #pragma unroll
        for (int i = 0; i < 8; ++i) {
            int r = rm + tm * 8 + i;
            float part = 0.f;
            #pragma unroll
            for (int j = 0; j < 8; ++j) part = fmaf(acc[i][j], wf[j], part);
            atomicAdd(&w[(size_t)r * cH + h], part);
        }
    }
}

// ------------- Kernel 4: fused bias-GEMM + attention + force (per (b,i)) -------------
__global__ __launch_bounds__(256) void attn_kernel(
    const float* __restrict__ pair, const float* __restrict__ mask,
    const float* __restrict__ dpos, const float* __restrict__ Q,
    const float* __restrict__ K, const float* __restrict__ w,
    const unsigned short* __restrict__ Wbp, const float* __restrict__ Sh_g,
    const float* __restrict__ cb_g, float* __restrict__ out)
{
    int bi = blockIdx.x;              // b*N + i
    int b = bi >> 9, i = bi & 511;
    int t = threadIdx.x;
    int lane = t & 63, wv = t >> 6;

    __shared__ __align__(16) unsigned short Ap[64 * 136];  // pair tile bf16 [j][p], padded
    __shared__ __align__(16) unsigned short Bw[32 * 136];  // Wb' bf16 [h][p], padded
    __shared__ float biasT[64][33];   // raw dots [j][h]
    __shared__ float qrow[512];
    __shared__ float mrow[64], rrow[64];
    __shared__ float mt[64][33];      // mask tile [j][h]; reused as reduce scratch at end
    __shared__ float dl[64][4];
    __shared__ float Shs[32], cbs[32];
    __shared__ float statred[64][8];

    // stage Wb' (once)
    {
        const ushort4* src = (const ushort4*)Wbp;
        #pragma unroll
        for (int s = 0; s < 4; ++s) {
            int f = t + 256 * s;      // 0..1023 ushort4 slots
            int hh = f >> 5, p4 = f & 31;
            ushort4 v = src[f];
            *(ushort4*)&Bw[hh * 136 + p4 * 4] = v;
        }
    }
    if (t < 128) {
        float4 qv = *(const float4*)(Q + (size_t)bi * cE + t * 4);
        *(float4*)&qrow[t * 4] = qv;
    }
    if (t < 32) { Shs[t] = Sh_g[t]; cbs[t] = cb_g[t]; }
    __syncthreads();

    int h = t & 31, js = t >> 5;      // softmax mapping: head h, j-slice js (8 slices)
    float qreg[16];
    #pragma unroll
    for (int d = 0; d < 16; ++d) qreg[d] = qrow[h * 16 + d];
    float Sh_loc = Shs[h], cb_loc = cbs[h];

    float m = -1e30f, l = 0.f, a0 = 0.f, a1 = 0.f, a2 = 0.f;

    const float* pbase = pair + (size_t)bi * cN * cP;
    const float* dbase = dpos + (size_t)bi * cN * 3;
    const float* Kbase = K + (size_t)b * cN * cE;
    const float* wbase = w + (size_t)b * cN * cH;

    for (int j0 = 0; j0 < cN; j0 += 64) {
        // ---- stage pair tile (f32 -> bf16) ----
        #pragma unroll
        for (int s = 0; s < 8; ++s) {
            int f = t + 256 * s;      // 0..2047 float4 slots
            int row = f >> 5, c4 = f & 31;
            float4 v = *(const float4*)(pbase + (size_t)(j0 + row) * cP + c4 * 4);
            ushort4 u;
            u.x = f2bf(v.x); u.y = f2bf(v.y); u.z = f2bf(v.z); u.w = f2bf(v.w);
            *(ushort4*)&Ap[row * 136 + c4 * 4] = u;
        }
        // ---- stage mask tile [j][h] ----
        #pragma unroll
        for (int s = 0; s < 2; ++s) {
            int f = t + 256 * s;      // 0..511
            int hh = f >> 4, c4 = f & 15;
            float4 v = *(const float4*)(mask + ((size_t)(b * cH + hh) * cN + i) * cN + j0 + c4 * 4);
            mt[c4 * 4 + 0][hh] = v.x; mt[c4 * 4 + 1][hh] = v.y;
            mt[c4 * 4 + 2][hh] = v.z; mt[c4 * 4 + 3][hh] = v.w;
        }
        // ---- stage delta ----
        if (t < 64) {
            const float* dp = dbase + (size_t)(j0 + t) * 3;
            dl[t][0] = dp[0]; dl[t][1] = dp[1]; dl[t][2] = dp[2];
        }
        __syncthreads();

        // ---- per-row mean/var from bf16 tile ----
        {
            int r = t >> 2, q = t & 3;
            float s1 = 0.f, s2 = 0.f;
            #pragma unroll
            for (int p = 0; p < 32; ++p) {
                float f = bf2f(Ap[r * 136 + q * 32 + p]);
                s1 += f; s2 = fmaf(f, f, s2);
            }
            statred[r][q] = s1; statred[r][q + 4] = s2;
        }
        __syncthreads();
        if (t < 64) {
            float s1 = statred[t][0] + statred[t][1] + statred[t][2] + statred[t][3];
            float s2 = statred[t][4] + statred[t][5] + statred[t][6] + statred[t][7];
            float mu = s1 * (1.0f / cP);
            float var = s2 * (1.0f / cP) - mu * mu;
            mrow[t] = mu;
            rrow[t] = rsqrtf(var + 1e-5f);
        }
        __syncthreads();

        // ---- MFMA raw dots: (64j x 128p) @ (128p x 32h) ----
        {
            f32x4 acc0 = {0.f, 0.f, 0.f, 0.f}, acc1 = {0.f, 0.f, 0.f, 0.f};
            int arow = wv * 16 + (lane & 15);
            int kq = (lane >> 4) * 8;
            #pragma unroll
            for (int kb = 0; kb < 4; ++kb) {
                int k = kb * 32 + kq;
                bf16x8 af = *(const bf16x8*)&Ap[arow * 136 + k];
                bf16x8 b0 = *(const bf16x8*)&Bw[(lane & 15) * 136 + k];
                bf16x8 b1 = *(const bf16x8*)&Bw[(16 + (lane & 15)) * 136 + k];
                acc0 = __builtin_amdgcn_mfma_f32_16x16x32_bf16(af, b0, acc0, 0, 0, 0);
                acc1 = __builtin_amdgcn_mfma_f32_16x16x32_bf16(af, b1, acc1, 0, 0, 0);
            }
            int crow = wv * 16 + (lane >> 4) * 4;
            int ccol = lane & 15;
            #pragma unroll
            for (int r = 0; r < 4; ++r) {
                biasT[crow + r][ccol] = acc0[r];
                biasT[crow + r][16 + ccol] = acc1[r];
            }
        }
        __syncthreads();

        // ---- logits + online softmax + accumulation ----
        #pragma unroll
        for (int jj = 0; jj < 8; ++jj) {
            int jr = js * 8 + jj;
            int j = j0 + jr;
            float bias = rrow[jr] * (biasT[jr][h] - mrow[jr] * Sh_loc) + cb_loc;
            const float4* kp4 = (const float4*)(Kbase + (size_t)j * cE + h * 16);
            float qk = 0.f;
            #pragma unroll
            for (int d4 = 0; d4 < 4; ++d4) {
                float4 kv = kp4[d4];
                qk = fmaf(qreg[d4 * 4 + 0], kv.x, qk);
                qk = fmaf(qreg[d4 * 4 + 1], kv.y, qk);
                qk = fmaf(qreg[d4 * 4 + 2], kv.z, qk);
                qk = fmaf(qreg[d4 * 4 + 3], kv.w, qk);
            }
            float z = qk + bias + mt[jr][h];
            float wj = wbase[(size_t)j * cH + h];
            float mn = fmaxf(m, z);
            float sc = __expf(m - mn);
            float p = __expf(z - mn);
            l = l * sc + p;
            float pw = p * wj;
            a0 = fmaf(pw, dl[jr][0], a0 * sc);
            a1 = fmaf(pw, dl[jr][1], a1 * sc);
            a2 = fmaf(pw, dl[jr][2], a2 * sc);
            m = mn;
        }
        __syncthreads();
    }

    // ---- merge 8 js-slices per head, then sum over heads ----
    float* red = (float*)mt;
    red[(h * 8 + js) * 6 + 0] = m;
    red[(h * 8 + js) * 6 + 1] = l;
    red[(h * 8 + js) * 6 + 2] = a0;
    red[(h * 8 + js) * 6 + 3] = a1;
    red[(h * 8 + js) * 6 + 4] = a2;
    __syncthreads();
    for (int s = 4; s >= 1; s >>= 1) {
        if (js < s) {
            float* p1 = &red[(h * 8 + js) * 6];
            float* p2 = &red[(h * 8 + js + s) * 6];
            float m1 = p1[0], m2 = p2[0];
            float mn = fmaxf(m1, m2);
            float s1 = __expf(m1 - mn), s2 = __expf(m2 - mn);
            p1[0] = mn;
            p1[1] = p1[1] * s1 + p2[1] * s2;
            p1[2] = p1[2] * s1 + p2[2] * s2;
            p1[3] = p1[3] * s1 + p2[3] * s2;
            p1[4] = p1[4] * s1 + p2[4] * s2;
        }
        __syncthreads();
    }
    if (js == 0) {
        float linv = 1.0f / red[h * 48 + 1];
        biasT[h][0] = red[h * 48 + 2] * linv;
        biasT[h][1] = red[h * 48 + 3] * linv;
        biasT[h][2] = red[h * 48 + 4] * linv;
    }
    __syncthreads();
    if (t < 3) {
        float s = 0.f;
        #pragma unroll
        for (int hh = 0; hh < cH; ++hh) s += biasT[hh][t];
        out[(size_t)bi * 3 + t] = s;
    }
}

// ---------------------------------------------------------------
extern "C" void kernel_launch(void* const* d_in, const int* in_sizes, int n_in,
                              void* d_out, int out_size, void* d_ws, size_t ws_size,
                              hipStream_t stream)
{
    const float* query = (const float*)d_in[0];
    const float* pair  = (const float*)d_in[1];
    const float* amask = (const float*)d_in[2];
    const float* dpos  = (const float*)d_in[3];
    const float* ln_g  = (const float*)d_in[4];
    const float* ln_b  = (const float*)d_in[5];
    const float* Wq    = (const float*)d_in[6];
    const float* Wk    = (const float*)d_in[7];
    const float* Wv    = (const float*)d_in[8];
    const float* pg    = (const float*)d_in[9];
    const float* pb    = (const float*)d_in[10];
    const float* Wb    = (const float*)d_in[11];
    const float* bbv   = (const float*)d_in[12];
    const float* Wf    = (const float*)d_in[13];
    float* out = (float*)d_out;

    char* ws = (char*)d_ws;
    float* xn = (float*)ws;                              // 4 MB
    float* Q  = (float*)(ws + (size_t)4 * 1048576);      // 4 MB
    float* K  = (float*)(ws + (size_t)8 * 1048576);      // 4 MB
    float* w  = (float*)(ws + (size_t)12 * 1048576);     // 256 KB
    unsigned short* Wbp = (unsigned short*)(ws + (size_t)12 * 1048576 + 262144); // 8 KB
    float* Sh  = (float*)(ws + (size_t)12 * 1048576 + 262144 + 8192);
    float* cbh = (float*)(ws + (size_t)12 * 1048576 + 262144 + 8192 + 128);

    ln_query_kernel<<<cB * cN, 256, 0, stream>>>(query, ln_g, ln_b, xn);
    setup_kernel<<<1, 64, 0, stream>>>(Wb, pg, pb, bbv, Wbp, Sh, cbh);
    hipMemsetAsync(w, 0, (size_t)cB * cN * cH * sizeof(float), stream);
    qkv_kernel<<<32 * 24, 64, 0, stream>>>(xn, Wq, Wk, Wv, Wf, Q, K, w);
    attn_kernel<<<cB * cN, 256, 0, stream>>>(pair, amask, dpos, Q, K, w, Wbp, Sh, cbh, out);
}